// Round 11
// baseline (20.671 us; speedup 1.0000x reference)
//
#include <hip/hip_runtime.h>
#include <hip/hip_bf16.h>
#include <hip/hip_fp16.h>

// out[b,j] = b2[j] + sum_k w2[j,k]*(h_k - tanh(h_k)), h_k = W_k·x + b1_k, x = y^3
// W = w1 with rows 0..19 replaced by saved_param.
//
// Exact decomposition: tanh(h) = 1 - 2r, r = 1/(1+exp2(c*h)), c = 2*log2(e):
//   out_j = E_j + A_j·x + g_j(y0,y1),   g_j(y) = sum_k 2*w2_jk * r_k(y)
//   E = b2 + w2·(b1-1),  A = w2·W_eff
// g tabulated on a 65x65 node grid over y in [-6,6]^2; nodes half2(g0,g1).
//
// Round 11: NO LDS in main. The LUT is stored as a 64x64 CELL table of 16B
// quads {n00,n10,n01,n11} (64 KB) and gathered directly per row with one
// global_load_dwordx4. Rationale (guide common-mistake #7): the table is
// L2-resident everywhere, and the Gaussian-concentrated access pattern makes
// the hot ~121 central cells (~2 KB) L1-resident. This deletes per-block
// staging + barrier + 16 LDS instrs/thread that round 10 showed were the
// critical path. Err: bilinear ~0.03 + fp16 ~0.003 vs threshold 0.142.

#define NHID 50
#define NVAR 20
#define LUTN 65
#define LUTSZ (LUTN * LUTN)       // 4225 nodes
#define CELLN 64                  // 64x64 cells
#define LUT_INVD 5.3333333f       // 64 / 12
#define LUT_CENT 32.0f            // 6 * 64/12
#define LUT_HIC  63.999f          // clamp so iu <= 63
#define QTAB_OFF 8                // float offset of quad table in ws (32B -> 16B aligned)

typedef float f4 __attribute__((ext_vector_type(4)));   // native vector for nt-store

// Fused prep + quad-table fill. 17 blocks x 256 threads; every block stages
// the tiny param set in LDS; block 0 additionally writes the E/A header.
// Each thread computes ONE node (exact exp2/rcp over 50 units) and scatters
// it into the <=4 cells that reference it (slot: 0=n00, 1=n10, 2=n01, 3=n11).
__global__ __launch_bounds__(256) void odefunc_lut(const float* __restrict__ w1,
                                                   const float* __restrict__ b1,
                                                   const float* __restrict__ w2,
                                                   const float* __restrict__ b2,
                                                   const float* __restrict__ sp,
                                                   float* __restrict__ ws) {
    __shared__ float cw0[NHID], cw1[NHID], cb[NHID], q0[NHID], q1[NHID];
    const float c = 2.8853900817779268f;  // 2*log2(e)
    int k = threadIdx.x;
    if (k < NHID) {
        float W0 = (k < NVAR) ? sp[2 * k]     : w1[2 * k];
        float W1 = (k < NVAR) ? sp[2 * k + 1] : w1[2 * k + 1];
        cw0[k] = c * W0;
        cw1[k] = c * W1;
        cb[k]  = c * b1[k];
        q0[k]  = 2.f * w2[k];           // w2 is [2,50] row-major
        q1[k]  = 2.f * w2[NHID + k];
    }
    if (blockIdx.x == 0 && k < 64) {
        // E/A header: 6-value wave reduction over units
        float W0 = 0.f, W1 = 0.f, bk = 0.f, w20 = 0.f, w21 = 0.f;
        if (k < NHID) {
            W0 = (k < NVAR) ? sp[2 * k]     : w1[2 * k];
            W1 = (k < NVAR) ? sp[2 * k + 1] : w1[2 * k + 1];
            bk  = b1[k];
            w20 = w2[k];
            w21 = w2[NHID + k];
        }
        float vals[6] = {w20 * W0, w20 * W1, w21 * W0, w21 * W1,
                         w20 * (bk - 1.f), w21 * (bk - 1.f)};
#pragma unroll
        for (int i = 0; i < 6; i++)
            for (int off = 32; off; off >>= 1)
                vals[i] += __shfl_xor(vals[i], off);
        if (k == 0) {
            ws[1] = b2[0] + vals[4];  // E0
            ws[2] = b2[1] + vals[5];  // E1
            ws[3] = vals[0];          // A00
            ws[4] = vals[1];          // A01
            ws[5] = vals[2];          // A10
            ws[6] = vals[3];          // A11
        }
    }
    __syncthreads();

    int idx = blockIdx.x * 256 + threadIdx.x;
    if (idx < LUTSZ) {
        int iy = idx / LUTN;
        int ix = idx - iy * LUTN;
        const float D = 12.0f / 64.0f;
        float y0 = -6.0f + ix * D;
        float y1 = -6.0f + iy * D;
        float x0 = y0 * y0 * y0, x1 = y1 * y1 * y1;
        float g0 = 0.f, g1 = 0.f;
        for (int kk = 0; kk < NHID; kk++) {
            float t = __builtin_amdgcn_exp2f(fmaf(cw0[kk], x0, fmaf(cw1[kk], x1, cb[kk])));
            float r = __builtin_amdgcn_rcpf(1.0f + t);  // t=inf -> r=0 exact
            g0 = fmaf(q0[kk], r, g0);
            g1 = fmaf(q1[kk], r, g1);
        }
        __half2 h = __floats2half2_rn(g0, g1);
        unsigned val = *(unsigned*)&h;

        unsigned* qtab = (unsigned*)(ws + QTAB_OFF);  // u32[64*64][4]
        // scatter node (ix,iy) into its owning cells
        if (ix < CELLN && iy < CELLN) qtab[4 * (iy * CELLN + ix) + 0]             = val; // n00
        if (ix >= 1   && iy < CELLN) qtab[4 * (iy * CELLN + (ix - 1)) + 1]        = val; // n10
        if (ix < CELLN && iy >= 1)   qtab[4 * ((iy - 1) * CELLN + ix) + 2]        = val; // n01
        if (ix >= 1   && iy >= 1)    qtab[4 * ((iy - 1) * CELLN + (ix - 1)) + 3]  = val; // n11
    }
}

__global__ __launch_bounds__(512) void odefunc_main(const float* __restrict__ y,
                                                    const float* __restrict__ wsf,
                                                    float* __restrict__ out,
                                                    int n4) {
    const float4* __restrict__ y4 = (const float4*)y;
    f4* __restrict__ o4 = (f4*)out;
    const uint4* __restrict__ qtab = (const uint4*)(wsf + QTAB_OFF);

    long long bbase = (long long)blockIdx.x * 2048;
    const bool full = (bbase + 2048) <= (long long)n4;   // uniform: no guards needed
    long long base = bbase + threadIdx.x;

    // issue all y-loads first (coalesced HBM stream)
    float4 vin[4];
    if (full) {
#pragma unroll
        for (int j = 0; j < 4; j++) vin[j] = y4[base + (long long)j * 512];
    } else {
#pragma unroll
        for (int j = 0; j < 4; j++) {
            long long idx = base + (long long)j * 512;
            vin[j] = (idx < n4) ? y4[idx] : make_float4(0.f, 0.f, 0.f, 0.f);
        }
    }

    // header: uniform -> scalar loads
    const float E0 = wsf[1], E1 = wsf[2];
    const float A00 = wsf[3], A01 = wsf[4], A10 = wsf[5], A11 = wsf[6];

#pragma unroll
    for (int g = 0; g < 2; g++) {   // 2 groups x 4 rows (= 2 float4s each)
        float ry0[4], ry1[4], fu[4], fv[4];
        uint4 q[4];
        // pass A: addresses + batched 16B gathers (4 outstanding dwordx4)
#pragma unroll
        for (int r = 0; r < 4; r++) {
            float4 v = vin[2 * g + (r >> 1)];
            float y0 = (r & 1) ? v.z : v.x;
            float y1 = (r & 1) ? v.w : v.y;
            ry0[r] = y0; ry1[r] = y1;
            float u  = fminf(fmaxf(fmaf(y0, LUT_INVD, LUT_CENT), 0.f), LUT_HIC);
            float vv = fminf(fmaxf(fmaf(y1, LUT_INVD, LUT_CENT), 0.f), LUT_HIC);
            int iu = (int)u, iv = (int)vv;
            fu[r] = u - (float)iu;
            fv[r] = vv - (float)iv;
            q[r] = qtab[iv * CELLN + iu];   // L1/L2-resident 16B quad
        }
        // pass B: fp16 bilinear lerps + linear part
        float o0[4], o1[4];
#pragma unroll
        for (int r = 0; r < 4; r++) {
            __half2 n00 = *(__half2*)&q[r].x, n10 = *(__half2*)&q[r].y;
            __half2 n01 = *(__half2*)&q[r].z, n11 = *(__half2*)&q[r].w;
            __half2 fu2 = __half2half2(__float2half_rn(fu[r]));
            __half2 fv2 = __half2half2(__float2half_rn(fv[r]));
            __half2 a  = __hfma2(fu2, __hsub2(n10, n00), n00);
            __half2 b  = __hfma2(fu2, __hsub2(n11, n01), n01);
            __half2 gg = __hfma2(fv2, __hsub2(b, a), a);
            float x0 = ry0[r] * ry0[r] * ry0[r];
            float x1 = ry1[r] * ry1[r] * ry1[r];
            o0[r] = fmaf(A00, x0, fmaf(A01, x1, E0)) + __half2float(__low2half(gg));
            o1[r] = fmaf(A10, x0, fmaf(A11, x1, E1)) + __half2float(__high2half(gg));
        }
        // stores (write-only stream -> nontemporal)
#pragma unroll
        for (int p = 0; p < 2; p++) {
            long long idx = base + (long long)(2 * g + p) * 512;
            f4 ov = {o0[2 * p], o1[2 * p], o0[2 * p + 1], o1[2 * p + 1]};
            if (full || idx < n4)
                __builtin_nontemporal_store(ov, &o4[idx]);
        }
    }
}

extern "C" void kernel_launch(void* const* d_in, const int* in_sizes, int n_in,
                              void* d_out, int out_size, void* d_ws, size_t ws_size,
                              hipStream_t stream) {
    // inputs: 0=t(int,1), 1=y(B*2), 2=w1(100), 3=b1(50), 4=w2(100), 5=b2(2), 6=saved_param(40)
    const float* y  = (const float*)d_in[1];
    const float* w1 = (const float*)d_in[2];
    const float* b1 = (const float*)d_in[3];
    const float* w2 = (const float*)d_in[4];
    const float* b2 = (const float*)d_in[5];
    const float* sp = (const float*)d_in[6];
    float* ws  = (float*)d_ws;
    float* out = (float*)d_out;

    int lut_blocks = (LUTSZ + 255) / 256;     // 17
    odefunc_lut<<<lut_blocks, 256, 0, stream>>>(w1, b1, w2, b2, sp, ws);

    int n4 = in_sizes[1] / 4;                 // number of float4s in y
    int blocks = (n4 + 2047) / 2048;          // 512 thr x 4 float4 each = 1024
    odefunc_main<<<blocks, 512, 0, stream>>>(y, ws, out, n4);
}

// Round 12
// 18.932 us; speedup vs baseline: 1.0919x; 1.0919x over previous
//
#include <hip/hip_runtime.h>
#include <hip/hip_bf16.h>
#include <hip/hip_fp16.h>

// out[b,j] = b2[j] + sum_k w2[j,k]*(h_k - tanh(h_k)), h_k = W_k·x + b1_k, x = y^3
// W = w1 with rows 0..19 replaced by saved_param.
//
// Exact decomposition: tanh(h) = 1 - 2r, r = 1/(1+exp2(c*h)), c = 2*log2(e):
//   out_j = E_j + A_j·x + g_j(y0,y1),   g_j(y) = sum_k 2*w2_jk * r_k(y)
//   E = b2 + w2·(b1-1),  A = w2·W_eff
// g tabulated on a 65x65 node grid over y in [-6,6]^2; nodes half2(g0,g1).
//
// Round 12: quad-packed LDS. LUT stored as 64x64 CELL table of 16B quads
// {n00,n10,n01,n11} (64 KB, filled by the 17-block lut kernel), staged to
// LDS, gathered with ONE ds_read_b128 per row (round 10 needed 2 ds_read2 +
// dual address math; round 11 showed global-gather is worse, 20.7 vs 18.4).
// 1024-thread blocks keep 2 blocks/CU = 32 waves/CU with the 64 KB table.
// Err: bilinear ~0.03 + fp16 ~0.003 vs threshold 0.142.

#define NHID 50
#define NVAR 20
#define LUTN 65
#define LUTSZ (LUTN * LUTN)       // 4225 nodes
#define CELLN 64                  // 64x64 cells
#define NQUAD (CELLN * CELLN)     // 4096 quads = 64 KB
#define LUT_INVD 5.3333333f       // 64 / 12
#define LUT_CENT 32.0f            // 6 * 64/12
#define LUT_HIC  63.999f          // clamp so iu <= 63
#define QTAB_OFF 8                // float offset of quad table in ws

typedef float f4 __attribute__((ext_vector_type(4)));   // native vector for nt-store

// Fused prep + quad-table fill. 17 blocks x 256 threads; every block stages
// the tiny param set in LDS; block 0 additionally writes the E/A header.
// Each thread computes ONE node (exact exp2/rcp over 50 units) and scatters
// it into the <=4 cells that reference it (slot: 0=n00, 1=n10, 2=n01, 3=n11).
__global__ __launch_bounds__(256) void odefunc_lut(const float* __restrict__ w1,
                                                   const float* __restrict__ b1,
                                                   const float* __restrict__ w2,
                                                   const float* __restrict__ b2,
                                                   const float* __restrict__ sp,
                                                   float* __restrict__ ws) {
    __shared__ float cw0[NHID], cw1[NHID], cb[NHID], q0[NHID], q1[NHID];
    const float c = 2.8853900817779268f;  // 2*log2(e)
    int k = threadIdx.x;
    if (k < NHID) {
        float W0 = (k < NVAR) ? sp[2 * k]     : w1[2 * k];
        float W1 = (k < NVAR) ? sp[2 * k + 1] : w1[2 * k + 1];
        cw0[k] = c * W0;
        cw1[k] = c * W1;
        cb[k]  = c * b1[k];
        q0[k]  = 2.f * w2[k];           // w2 is [2,50] row-major
        q1[k]  = 2.f * w2[NHID + k];
    }
    if (blockIdx.x == 0 && k < 64) {
        // E/A header: 6-value wave reduction over units
        float W0 = 0.f, W1 = 0.f, bk = 0.f, w20 = 0.f, w21 = 0.f;
        if (k < NHID) {
            W0 = (k < NVAR) ? sp[2 * k]     : w1[2 * k];
            W1 = (k < NVAR) ? sp[2 * k + 1] : w1[2 * k + 1];
            bk  = b1[k];
            w20 = w2[k];
            w21 = w2[NHID + k];
        }
        float vals[6] = {w20 * W0, w20 * W1, w21 * W0, w21 * W1,
                         w20 * (bk - 1.f), w21 * (bk - 1.f)};
#pragma unroll
        for (int i = 0; i < 6; i++)
            for (int off = 32; off; off >>= 1)
                vals[i] += __shfl_xor(vals[i], off);
        if (k == 0) {
            ws[1] = b2[0] + vals[4];  // E0
            ws[2] = b2[1] + vals[5];  // E1
            ws[3] = vals[0];          // A00
            ws[4] = vals[1];          // A01
            ws[5] = vals[2];          // A10
            ws[6] = vals[3];          // A11
        }
    }
    __syncthreads();

    int idx = blockIdx.x * 256 + threadIdx.x;
    if (idx < LUTSZ) {
        int iy = idx / LUTN;
        int ix = idx - iy * LUTN;
        const float D = 12.0f / 64.0f;
        float y0 = -6.0f + ix * D;
        float y1 = -6.0f + iy * D;
        float x0 = y0 * y0 * y0, x1 = y1 * y1 * y1;
        float g0 = 0.f, g1 = 0.f;
        for (int kk = 0; kk < NHID; kk++) {
            float t = __builtin_amdgcn_exp2f(fmaf(cw0[kk], x0, fmaf(cw1[kk], x1, cb[kk])));
            float r = __builtin_amdgcn_rcpf(1.0f + t);  // t=inf -> r=0 exact
            g0 = fmaf(q0[kk], r, g0);
            g1 = fmaf(q1[kk], r, g1);
        }
        __half2 h = __floats2half2_rn(g0, g1);
        unsigned val = *(unsigned*)&h;

        unsigned* qtab = (unsigned*)(ws + QTAB_OFF);  // u32[4096][4]
        // scatter node (ix,iy) into its owning cells
        if (ix < CELLN && iy < CELLN) qtab[4 * (iy * CELLN + ix) + 0]             = val; // n00
        if (ix >= 1   && iy < CELLN) qtab[4 * (iy * CELLN + (ix - 1)) + 1]        = val; // n10
        if (ix < CELLN && iy >= 1)   qtab[4 * ((iy - 1) * CELLN + ix) + 2]        = val; // n01
        if (ix >= 1   && iy >= 1)    qtab[4 * ((iy - 1) * CELLN + (ix - 1)) + 3]  = val; // n11
    }
}

__global__ __launch_bounds__(1024) void odefunc_main(const float* __restrict__ y,
                                                     const float* __restrict__ wsf,
                                                     float* __restrict__ out,
                                                     int n4) {
    __shared__ __align__(16) uint4 lutq[NQUAD];   // 64 KB cell-quad table
    const float4* __restrict__ y4 = (const float4*)y;
    f4* __restrict__ o4 = (f4*)out;

    long long bbase = (long long)blockIdx.x * 4096;
    const bool full = (bbase + 4096) <= (long long)n4;   // uniform: no guards needed
    long long base = bbase + threadIdx.x;

    // issue y-loads FIRST so HBM latency hides under staging + barrier
    float4 vin[4];
    if (full) {
#pragma unroll
        for (int j = 0; j < 4; j++) vin[j] = y4[base + (long long)j * 1024];
    } else {
#pragma unroll
        for (int j = 0; j < 4; j++) {
            long long idx = base + (long long)j * 1024;
            vin[j] = (idx < n4) ? y4[idx] : make_float4(0.f, 0.f, 0.f, 0.f);
        }
    }

    // stage quad table (4096 x 16B; 4 uint4 per thread)
    const uint4* __restrict__ glut4 = (const uint4*)(wsf + QTAB_OFF);
    for (int i = threadIdx.x; i < NQUAD; i += 1024) lutq[i] = glut4[i];

    const float E0 = wsf[1], E1 = wsf[2];
    const float A00 = wsf[3], A01 = wsf[4], A10 = wsf[5], A11 = wsf[6];
    __syncthreads();

#pragma unroll
    for (int g = 0; g < 2; g++) {   // 2 groups x 4 rows (= 2 float4s each)
        float ry0[4], ry1[4], fu[4], fv[4];
        uint4 q[4];
        // pass A: addresses + batched LDS issue (4 ds_read_b128 back-to-back)
#pragma unroll
        for (int r = 0; r < 4; r++) {
            float4 v = vin[2 * g + (r >> 1)];
            float y0 = (r & 1) ? v.z : v.x;
            float y1 = (r & 1) ? v.w : v.y;
            ry0[r] = y0; ry1[r] = y1;
            float u  = fminf(fmaxf(fmaf(y0, LUT_INVD, LUT_CENT), 0.f), LUT_HIC);
            float vv = fminf(fmaxf(fmaf(y1, LUT_INVD, LUT_CENT), 0.f), LUT_HIC);
            int iu = (int)u, iv = (int)vv;
            fu[r] = u - (float)iu;
            fv[r] = vv - (float)iv;
            q[r] = lutq[(iv << 6) | iu];   // ONE ds_read_b128 per row
        }
        // pass B: fp16 bilinear lerps + linear part
        float o0[4], o1[4];
#pragma unroll
        for (int r = 0; r < 4; r++) {
            __half2 n00 = *(__half2*)&q[r].x, n10 = *(__half2*)&q[r].y;
            __half2 n01 = *(__half2*)&q[r].z, n11 = *(__half2*)&q[r].w;
            __half2 fu2 = __half2half2(__float2half_rn(fu[r]));
            __half2 fv2 = __half2half2(__float2half_rn(fv[r]));
            __half2 a  = __hfma2(fu2, __hsub2(n10, n00), n00);
            __half2 b  = __hfma2(fu2, __hsub2(n11, n01), n01);
            __half2 gg = __hfma2(fv2, __hsub2(b, a), a);
            float x0 = ry0[r] * ry0[r] * ry0[r];
            float x1 = ry1[r] * ry1[r] * ry1[r];
            o0[r] = fmaf(A00, x0, fmaf(A01, x1, E0)) + __half2float(__low2half(gg));
            o1[r] = fmaf(A10, x0, fmaf(A11, x1, E1)) + __half2float(__high2half(gg));
        }
        // stores (write-only stream -> nontemporal)
#pragma unroll
        for (int p = 0; p < 2; p++) {
            long long idx = base + (long long)(2 * g + p) * 1024;
            f4 ov = {o0[2 * p], o1[2 * p], o0[2 * p + 1], o1[2 * p + 1]};
            if (full || idx < n4)
                __builtin_nontemporal_store(ov, &o4[idx]);
        }
    }
}

extern "C" void kernel_launch(void* const* d_in, const int* in_sizes, int n_in,
                              void* d_out, int out_size, void* d_ws, size_t ws_size,
                              hipStream_t stream) {
    // inputs: 0=t(int,1), 1=y(B*2), 2=w1(100), 3=b1(50), 4=w2(100), 5=b2(2), 6=saved_param(40)
    const float* y  = (const float*)d_in[1];
    const float* w1 = (const float*)d_in[2];
    const float* b1 = (const float*)d_in[3];
    const float* w2 = (const float*)d_in[4];
    const float* b2 = (const float*)d_in[5];
    const float* sp = (const float*)d_in[6];
    float* ws  = (float*)d_ws;
    float* out = (float*)d_out;

    int lut_blocks = (LUTSZ + 255) / 256;     // 17
    odefunc_lut<<<lut_blocks, 256, 0, stream>>>(w1, b1, w2, b2, sp, ws);

    int n4 = in_sizes[1] / 4;                 // number of float4s in y
    int blocks = (n4 + 4095) / 4096;          // 1024 thr x 4 float4 each = 512
    odefunc_main<<<blocks, 1024, 0, stream>>>(y, ws, out, n4);
}

// Round 13
// 18.930 us; speedup vs baseline: 1.0920x; 1.0001x over previous
//
#include <hip/hip_runtime.h>
#include <hip/hip_bf16.h>
#include <hip/hip_fp16.h>

// out[b,j] = b2[j] + sum_k w2[j,k]*(h_k - tanh(h_k)), h_k = W_k·x + b1_k, x = y^3
// W = w1 with rows 0..19 replaced by saved_param.
//
// Exact decomposition: tanh(h) = 1 - 2r, r = 1/(1+exp2(c*h)), c = 2*log2(e):
//   out_j = E_j + A_j·x + g_j(y0,y1),   g_j(y) = sum_k 2*w2_jk * r_k(y)
//   E = b2 + w2·(b1-1),  A = w2·W_eff
// g tabulated on a 65x65 node grid over y in [-6,6]^2 (17-block fill kernel,
// exact exp2/rcp), nodes packed half2(g0,g1) -> 16.9 KB LDS table, bilinear
// via 2 ds_read2_b32/row + v_pk_fma_f16 lerp. Err ~0.03 vs threshold 0.142.
//
// Round 13: round-10 winner structure (node table + batch-4 LDS ILP) with
// 256-thread blocks x 2048: 4x narrower barriers, exact grid (every block
// full, zero tail), 8 independent blocks/CU interleaving staging/compute
// (round 12's b128 quad table regressed: 4 banks/lane + 64KB staging).

#define NHID 50
#define NVAR 20
#define LUTN 65
#define LUTSZ (LUTN * LUTN)       // 4225
#define LUT_INVD 5.3333333f       // 64 / 12
#define LUT_CENT 32.0f            // 6 * 64/12
#define LUT_HIC  63.999f          // clamp so iu+1 <= 64

typedef float f4 __attribute__((ext_vector_type(4)));   // native vector for nt-store

// Fused prep + LUT fill. 17 blocks x 256 threads; every block recomputes the
// tiny param set locally (LDS); block 0 additionally writes the E/A header.
__global__ __launch_bounds__(256) void odefunc_lut(const float* __restrict__ w1,
                                                   const float* __restrict__ b1,
                                                   const float* __restrict__ w2,
                                                   const float* __restrict__ b2,
                                                   const float* __restrict__ sp,
                                                   float* __restrict__ ws) {
    __shared__ float cw0[NHID], cw1[NHID], cb[NHID], q0[NHID], q1[NHID];
    const float c = 2.8853900817779268f;  // 2*log2(e)
    int k = threadIdx.x;
    if (k < NHID) {
        float W0 = (k < NVAR) ? sp[2 * k]     : w1[2 * k];
        float W1 = (k < NVAR) ? sp[2 * k + 1] : w1[2 * k + 1];
        cw0[k] = c * W0;
        cw1[k] = c * W1;
        cb[k]  = c * b1[k];
        q0[k]  = 2.f * w2[k];           // w2 is [2,50] row-major
        q1[k]  = 2.f * w2[NHID + k];
    }
    if (blockIdx.x == 0 && k < 64) {
        // E/A header: 6-value wave reduction over units
        float W0 = 0.f, W1 = 0.f, bk = 0.f, w20 = 0.f, w21 = 0.f;
        if (k < NHID) {
            W0 = (k < NVAR) ? sp[2 * k]     : w1[2 * k];
            W1 = (k < NVAR) ? sp[2 * k + 1] : w1[2 * k + 1];
            bk  = b1[k];
            w20 = w2[k];
            w21 = w2[NHID + k];
        }
        float vals[6] = {w20 * W0, w20 * W1, w21 * W0, w21 * W1,
                         w20 * (bk - 1.f), w21 * (bk - 1.f)};
#pragma unroll
        for (int i = 0; i < 6; i++)
            for (int off = 32; off; off >>= 1)
                vals[i] += __shfl_xor(vals[i], off);
        if (k == 0) {
            ws[1] = b2[0] + vals[4];  // E0
            ws[2] = b2[1] + vals[5];  // E1
            ws[3] = vals[0];          // A00
            ws[4] = vals[1];          // A01
            ws[5] = vals[2];          // A10
            ws[6] = vals[3];          // A11
        }
    }
    __syncthreads();

    int idx = blockIdx.x * 256 + threadIdx.x;
    if (idx < LUTSZ) {
        int iy = idx / LUTN;
        int ix = idx - iy * LUTN;
        const float D = 12.0f / 64.0f;
        float y0 = -6.0f + ix * D;
        float y1 = -6.0f + iy * D;
        float x0 = y0 * y0 * y0, x1 = y1 * y1 * y1;
        float g0 = 0.f, g1 = 0.f;
        for (int kk = 0; kk < NHID; kk++) {
            float t = __builtin_amdgcn_exp2f(fmaf(cw0[kk], x0, fmaf(cw1[kk], x1, cb[kk])));
            float r = __builtin_amdgcn_rcpf(1.0f + t);  // t=inf -> r=0 exact
            g0 = fmaf(q0[kk], r, g0);
            g1 = fmaf(q1[kk], r, g1);
        }
        __half2 h = __floats2half2_rn(g0, g1);
        ((unsigned*)(ws + 8))[idx] = *(unsigned*)&h;
    }
}

__global__ __launch_bounds__(256) void odefunc_main(const float* __restrict__ y,
                                                    const float* __restrict__ wsf,
                                                    float* __restrict__ out,
                                                    int n4) {
    __shared__ __align__(16) unsigned lut[LUTSZ + 3];   // +3 pad for uint4 staging
    const float4* __restrict__ y4 = (const float4*)y;
    f4* __restrict__ o4 = (f4*)out;

    long long bbase = (long long)blockIdx.x * 1024;
    const bool full = (bbase + 1024) <= (long long)n4;   // exact grid: always true
    long long base = bbase + threadIdx.x;

    // issue y-loads FIRST so HBM latency hides under staging + barrier
    float4 vin[4];
    if (full) {
#pragma unroll
        for (int j = 0; j < 4; j++) vin[j] = y4[base + (long long)j * 256];
    } else {
#pragma unroll
        for (int j = 0; j < 4; j++) {
            long long idx = base + (long long)j * 256;
            vin[j] = (idx < n4) ? y4[idx] : make_float4(0.f, 0.f, 0.f, 0.f);
        }
    }

    // stage LUT with uint4 loads (1057 x 16B over 256 threads)
    const uint4* __restrict__ glut4 = (const uint4*)(wsf + 8);
    uint4* lut4 = (uint4*)lut;
    for (int i = threadIdx.x; i < (LUTSZ + 3) / 4; i += 256) lut4[i] = glut4[i];

    const float E0 = wsf[1], E1 = wsf[2];
    const float A00 = wsf[3], A01 = wsf[4], A10 = wsf[5], A11 = wsf[6];
    __syncthreads();

#pragma unroll
    for (int g = 0; g < 2; g++) {   // 2 groups x 4 rows (= 2 float4s each)
        float ry0[4], ry1[4], fu[4], fv[4];
        unsigned u00[4], u10[4], u01[4], u11[4];
        // pass A: addresses + batched LDS issue (8 ds_read2 back-to-back)
#pragma unroll
        for (int r = 0; r < 4; r++) {
            float4 v = vin[2 * g + (r >> 1)];
            float y0 = (r & 1) ? v.z : v.x;
            float y1 = (r & 1) ? v.w : v.y;
            ry0[r] = y0; ry1[r] = y1;
            float u  = fminf(fmaxf(fmaf(y0, LUT_INVD, LUT_CENT), 0.f), LUT_HIC);
            float vv = fminf(fmaxf(fmaf(y1, LUT_INVD, LUT_CENT), 0.f), LUT_HIC);
            int iu = (int)u, iv = (int)vv;
            fu[r] = u - (float)iu;
            fv[r] = vv - (float)iv;
            int id = iv * LUTN + iu;
            u00[r] = lut[id];          u10[r] = lut[id + 1];
            u01[r] = lut[id + LUTN];   u11[r] = lut[id + LUTN + 1];
        }
        // pass B: fp16 bilinear lerps + linear part
        float o0[4], o1[4];
#pragma unroll
        for (int r = 0; r < 4; r++) {
            __half2 n00 = *(__half2*)&u00[r], n10 = *(__half2*)&u10[r];
            __half2 n01 = *(__half2*)&u01[r], n11 = *(__half2*)&u11[r];
            __half2 fu2 = __half2half2(__float2half_rn(fu[r]));
            __half2 fv2 = __half2half2(__float2half_rn(fv[r]));
            __half2 a  = __hfma2(fu2, __hsub2(n10, n00), n00);
            __half2 b  = __hfma2(fu2, __hsub2(n11, n01), n01);
            __half2 gg = __hfma2(fv2, __hsub2(b, a), a);
            float x0 = ry0[r] * ry0[r] * ry0[r];
            float x1 = ry1[r] * ry1[r] * ry1[r];
            o0[r] = fmaf(A00, x0, fmaf(A01, x1, E0)) + __half2float(__low2half(gg));
            o1[r] = fmaf(A10, x0, fmaf(A11, x1, E1)) + __half2float(__high2half(gg));
        }
        // stores (write-only stream -> nontemporal)
#pragma unroll
        for (int p = 0; p < 2; p++) {
            long long idx = base + (long long)(2 * g + p) * 256;
            f4 ov = {o0[2 * p], o1[2 * p], o0[2 * p + 1], o1[2 * p + 1]};
            if (full || idx < n4)
                __builtin_nontemporal_store(ov, &o4[idx]);
        }
    }
}

extern "C" void kernel_launch(void* const* d_in, const int* in_sizes, int n_in,
                              void* d_out, int out_size, void* d_ws, size_t ws_size,
                              hipStream_t stream) {
    // inputs: 0=t(int,1), 1=y(B*2), 2=w1(100), 3=b1(50), 4=w2(100), 5=b2(2), 6=saved_param(40)
    const float* y  = (const float*)d_in[1];
    const float* w1 = (const float*)d_in[2];
    const float* b1 = (const float*)d_in[3];
    const float* w2 = (const float*)d_in[4];
    const float* b2 = (const float*)d_in[5];
    const float* sp = (const float*)d_in[6];
    float* ws  = (float*)d_ws;
    float* out = (float*)d_out;

    int lut_blocks = (LUTSZ + 255) / 256;     // 17
    odefunc_lut<<<lut_blocks, 256, 0, stream>>>(w1, b1, w2, b2, sp, ws);

    int n4 = in_sizes[1] / 4;                 // number of float4s in y
    int blocks = (n4 + 1023) / 1024;          // 256 thr x 4 float4 each = 2048
    odefunc_main<<<blocks, 256, 0, stream>>>(y, ws, out, n4);
}

// Round 14
// 18.118 us; speedup vs baseline: 1.1409x; 1.0448x over previous
//
#include <hip/hip_runtime.h>
#include <hip/hip_bf16.h>
#include <hip/hip_fp16.h>

// out[b,j] = b2[j] + sum_k w2[j,k]*(h_k - tanh(h_k)), h_k = W_k·x + b1_k, x = y^3
// W = w1 with rows 0..19 replaced by saved_param.
//
// Exact decomposition: tanh(h) = 1 - 2r, r = 1/(1+exp2(c*h)), c = 2*log2(e):
//   out_j = E_j + A_j·x + g_j(y0,y1),   g_j(y) = sum_k 2*w2_jk * r_k(y)
//   E = b2 + w2·(b1-1),  A = w2·W_eff
// g tabulated on a 65x65 node grid over y in [-6,6]^2 (17-block fill kernel,
// exact exp2/rcp), nodes packed half2(g0,g1) -> 16.9 KB LDS table, bilinear
// via 2 ds_read2_b32/row + v_pk_fma_f16 lerp. Err ~0.03 vs threshold 0.142.
//
// FINAL (= round-10 winner, 18.43us): 512-thr x 1024 blocks, rows batched x4
// with all ds_reads issued into register arrays before any lerp (LDS-ILP),
// uint4 LUT staging, uniform full-block guard hoisting, nontemporal stores.
// Probed and rejected: packed-f32 direct eval (47us, VALU-bound), global
// L1 gather (20.7us), b128 quad table (18.9us), 256-thr blocks (18.9us),
// cooperative single-kernel (105us/dispatch). Structure is at its practical
// roofline: main ~15.5us vs ~12.5-13us mixed-stream memory floor + ~3us
// fixed lut-kernel/launch overhead.

#define NHID 50
#define NVAR 20
#define LUTN 65
#define LUTSZ (LUTN * LUTN)       // 4225
#define LUT_INVD 5.3333333f       // 64 / 12
#define LUT_CENT 32.0f            // 6 * 64/12
#define LUT_HIC  63.999f          // clamp so iu+1 <= 64

typedef float f4 __attribute__((ext_vector_type(4)));   // native vector for nt-store

// Fused prep + LUT fill. 17 blocks x 256 threads; every block recomputes the
// tiny param set locally (LDS); block 0 additionally writes the E/A header.
__global__ __launch_bounds__(256) void odefunc_lut(const float* __restrict__ w1,
                                                   const float* __restrict__ b1,
                                                   const float* __restrict__ w2,
                                                   const float* __restrict__ b2,
                                                   const float* __restrict__ sp,
                                                   float* __restrict__ ws) {
    __shared__ float cw0[NHID], cw1[NHID], cb[NHID], q0[NHID], q1[NHID];
    const float c = 2.8853900817779268f;  // 2*log2(e)
    int k = threadIdx.x;
    if (k < NHID) {
        float W0 = (k < NVAR) ? sp[2 * k]     : w1[2 * k];
        float W1 = (k < NVAR) ? sp[2 * k + 1] : w1[2 * k + 1];
        cw0[k] = c * W0;
        cw1[k] = c * W1;
        cb[k]  = c * b1[k];
        q0[k]  = 2.f * w2[k];           // w2 is [2,50] row-major
        q1[k]  = 2.f * w2[NHID + k];
    }
    if (blockIdx.x == 0 && k < 64) {
        // E/A header: 6-value wave reduction over units
        float W0 = 0.f, W1 = 0.f, bk = 0.f, w20 = 0.f, w21 = 0.f;
        if (k < NHID) {
            W0 = (k < NVAR) ? sp[2 * k]     : w1[2 * k];
            W1 = (k < NVAR) ? sp[2 * k + 1] : w1[2 * k + 1];
            bk  = b1[k];
            w20 = w2[k];
            w21 = w2[NHID + k];
        }
        float vals[6] = {w20 * W0, w20 * W1, w21 * W0, w21 * W1,
                         w20 * (bk - 1.f), w21 * (bk - 1.f)};
#pragma unroll
        for (int i = 0; i < 6; i++)
            for (int off = 32; off; off >>= 1)
                vals[i] += __shfl_xor(vals[i], off);
        if (k == 0) {
            ws[1] = b2[0] + vals[4];  // E0
            ws[2] = b2[1] + vals[5];  // E1
            ws[3] = vals[0];          // A00
            ws[4] = vals[1];          // A01
            ws[5] = vals[2];          // A10
            ws[6] = vals[3];          // A11
        }
    }
    __syncthreads();

    int idx = blockIdx.x * 256 + threadIdx.x;
    if (idx < LUTSZ) {
        int iy = idx / LUTN;
        int ix = idx - iy * LUTN;
        const float D = 12.0f / 64.0f;
        float y0 = -6.0f + ix * D;
        float y1 = -6.0f + iy * D;
        float x0 = y0 * y0 * y0, x1 = y1 * y1 * y1;
        float g0 = 0.f, g1 = 0.f;
        for (int kk = 0; kk < NHID; kk++) {
            float t = __builtin_amdgcn_exp2f(fmaf(cw0[kk], x0, fmaf(cw1[kk], x1, cb[kk])));
            float r = __builtin_amdgcn_rcpf(1.0f + t);  // t=inf -> r=0 exact
            g0 = fmaf(q0[kk], r, g0);
            g1 = fmaf(q1[kk], r, g1);
        }
        __half2 h = __floats2half2_rn(g0, g1);
        ((unsigned*)(ws + 8))[idx] = *(unsigned*)&h;
    }
}

__global__ __launch_bounds__(512) void odefunc_main(const float* __restrict__ y,
                                                    const float* __restrict__ wsf,
                                                    float* __restrict__ out,
                                                    int n4) {
    __shared__ __align__(16) unsigned lut[LUTSZ + 3];   // +3 pad for uint4 staging
    const float4* __restrict__ y4 = (const float4*)y;
    f4* __restrict__ o4 = (f4*)out;

    long long bbase = (long long)blockIdx.x * 2048;
    const bool full = (bbase + 2048) <= (long long)n4;   // uniform: no guards needed
    long long base = bbase + threadIdx.x;

    // issue y-loads FIRST so HBM latency hides under staging + barrier
    float4 vin[4];
    if (full) {
#pragma unroll
        for (int j = 0; j < 4; j++) vin[j] = y4[base + (long long)j * 512];
    } else {
#pragma unroll
        for (int j = 0; j < 4; j++) {
            long long idx = base + (long long)j * 512;
            vin[j] = (idx < n4) ? y4[idx] : make_float4(0.f, 0.f, 0.f, 0.f);
        }
    }

    // stage LUT with uint4 loads (1057 x 16B)
    const uint4* __restrict__ glut4 = (const uint4*)(wsf + 8);
    uint4* lut4 = (uint4*)lut;
    for (int i = threadIdx.x; i < (LUTSZ + 3) / 4; i += 512) lut4[i] = glut4[i];

    const float E0 = wsf[1], E1 = wsf[2];
    const float A00 = wsf[3], A01 = wsf[4], A10 = wsf[5], A11 = wsf[6];
    __syncthreads();

#pragma unroll
    for (int g = 0; g < 2; g++) {   // 2 groups x 4 rows (= 2 float4s each)
        float ry0[4], ry1[4], fu[4], fv[4];
        unsigned u00[4], u10[4], u01[4], u11[4];
        // pass A: addresses + batched LDS issue (8 ds_read2 back-to-back)
#pragma unroll
        for (int r = 0; r < 4; r++) {
            float4 v = vin[2 * g + (r >> 1)];
            float y0 = (r & 1) ? v.z : v.x;
            float y1 = (r & 1) ? v.w : v.y;
            ry0[r] = y0; ry1[r] = y1;
            float u  = fminf(fmaxf(fmaf(y0, LUT_INVD, LUT_CENT), 0.f), LUT_HIC);
            float vv = fminf(fmaxf(fmaf(y1, LUT_INVD, LUT_CENT), 0.f), LUT_HIC);
            int iu = (int)u, iv = (int)vv;
            fu[r] = u - (float)iu;
            fv[r] = vv - (float)iv;
            int id = iv * LUTN + iu;
            u00[r] = lut[id];          u10[r] = lut[id + 1];
            u01[r] = lut[id + LUTN];   u11[r] = lut[id + LUTN + 1];
        }
        // pass B: fp16 bilinear lerps + linear part
        float o0[4], o1[4];
#pragma unroll
        for (int r = 0; r < 4; r++) {
            __half2 n00 = *(__half2*)&u00[r], n10 = *(__half2*)&u10[r];
            __half2 n01 = *(__half2*)&u01[r], n11 = *(__half2*)&u11[r];
            __half2 fu2 = __half2half2(__float2half_rn(fu[r]));
            __half2 fv2 = __half2half2(__float2half_rn(fv[r]));
            __half2 a  = __hfma2(fu2, __hsub2(n10, n00), n00);
            __half2 b  = __hfma2(fu2, __hsub2(n11, n01), n01);
            __half2 gg = __hfma2(fv2, __hsub2(b, a), a);
            float x0 = ry0[r] * ry0[r] * ry0[r];
            float x1 = ry1[r] * ry1[r] * ry1[r];
            o0[r] = fmaf(A00, x0, fmaf(A01, x1, E0)) + __half2float(__low2half(gg));
            o1[r] = fmaf(A10, x0, fmaf(A11, x1, E1)) + __half2float(__high2half(gg));
        }
        // stores (write-only stream -> nontemporal)
#pragma unroll
        for (int p = 0; p < 2; p++) {
            long long idx = base + (long long)(2 * g + p) * 512;
            f4 ov = {o0[2 * p], o1[2 * p], o0[2 * p + 1], o1[2 * p + 1]};
            if (full || idx < n4)
                __builtin_nontemporal_store(ov, &o4[idx]);
        }
    }
}

extern "C" void kernel_launch(void* const* d_in, const int* in_sizes, int n_in,
                              void* d_out, int out_size, void* d_ws, size_t ws_size,
                              hipStream_t stream) {
    // inputs: 0=t(int,1), 1=y(B*2), 2=w1(100), 3=b1(50), 4=w2(100), 5=b2(2), 6=saved_param(40)
    const float* y  = (const float*)d_in[1];
    const float* w1 = (const float*)d_in[2];
    const float* b1 = (const float*)d_in[3];
    const float* w2 = (const float*)d_in[4];
    const float* b2 = (const float*)d_in[5];
    const float* sp = (const float*)d_in[6];
    float* ws  = (float*)d_ws;
    float* out = (float*)d_out;

    int lut_blocks = (LUTSZ + 255) / 256;     // 17
    odefunc_lut<<<lut_blocks, 256, 0, stream>>>(w1, b1, w2, b2, sp, ws);

    int n4 = in_sizes[1] / 4;                 // number of float4s in y
    int blocks = (n4 + 2047) / 2048;          // 512 thr x 4 float4 each = 1024
    odefunc_main<<<blocks, 512, 0, stream>>>(y, ws, out, n4);
}